// Round 12
// baseline (209.648 us; speedup 1.0000x reference)
//
#include <hip/hip_runtime.h>
#include <stdint.h>

// ---- problem constants ----
#define Bz 8
#define Tz 1024
#define Cz 768
#define Hz 8
#define Dz 96
#define BHz 64            // Bz*Hz
#define Kz 768

typedef __bf16 bf16x8 __attribute__((ext_vector_type(8)));
typedef unsigned short u16x8 __attribute__((ext_vector_type(8)));
typedef float f32x4 __attribute__((ext_vector_type(4)));

__device__ __forceinline__ unsigned short f2bf(float f) {
  union { float f; unsigned int u; } v; v.f = f;
  unsigned int u = v.u;
  return (unsigned short)((u + 0x7fffu + ((u >> 16) & 1u)) >> 16);
}

// pack two f32 -> one dword of 2x bf16 (lo=a, hi=b); gfx950 hw instr (guide T12)
__device__ __forceinline__ unsigned int cvtpk(float a, float b) {
  unsigned int r;
  asm("v_cvt_pk_bf16_f32 %0, %1, %2" : "=v"(r) : "v"(a), "v"(b));
  return r;
}

#if defined(__has_builtin)
#if __has_builtin(__builtin_amdgcn_exp2f)
#define EXP2(x) __builtin_amdgcn_exp2f(x)
#endif
#endif
#ifndef EXP2
#define EXP2(x) __expf((x) * 0.6931471805599453f)
#endif

// async global->LDS, 16B per lane; LDS dest must be wave-uniform base (+lane*16 implicit)
typedef const __attribute__((address_space(1))) void* gas_ptr;
typedef __attribute__((address_space(3))) void* las_ptr;
__device__ __forceinline__ void gl16(const void* g, void* l) {
  __builtin_amdgcn_global_load_lds((gas_ptr)g, (las_ptr)l, 16, 0, 0);
}

// ---- prep: weight transposes only (x-cast is fused into gemm_qkv) ----
// blocks 0..431: Wa (36x12 tiles); 432..575: Wp (12x12 tiles)
__global__ __launch_bounds__(256) void prep(const float* __restrict__ Wa,
                                            unsigned short* __restrict__ Wat,
                                            const float* __restrict__ Wp,
                                            unsigned short* __restrict__ Wpt) {
  __shared__ unsigned short t[64][72];
  const int bid = blockIdx.x;
  const int tid = threadIdx.x;
  const float* in; unsigned short* out; int R, Cc, bx, by;
  if (bid < 432) { int q = bid;       in = Wa; out = Wat; R = 768; Cc = 2304; bx = (q % 36) * 64; by = (q / 36) * 64; }
  else           { int q = bid - 432; in = Wp; out = Wpt; R = 768; Cc = 768;  bx = (q % 12) * 64; by = (q / 12) * 64; }
#pragma unroll
  for (int i = 0; i < 16; i++) {
    int idx = tid + i * 256;
    int r = idx >> 6, c = idx & 63;
    t[c][r] = f2bf(in[(by + r) * Cc + bx + c]);
  }
  __syncthreads();
#pragma unroll
  for (int i = 0; i < 16; i++) {
    int idx = tid + i * 256;
    int r = idx >> 6, c = idx & 63;
    out[(bx + r) * R + by + c] = t[r][c];
  }
}

// ---- gemm_qkv: [8192x768 fp32 x] @ [Wat 2304x768 bf16]^T -> qkv, 128x128, BK=32 ----
// A-path FUSES the x fp32->bf16 cast: reg-stage (float4 loads -> v_cvt_pk_bf16_f32 ->
// swizzled ds_write_b128), T14 split (loads at iter top, writes before the barrier).
// B-path: gl16 direct with source pre-swizzle (validated: bank conflicts = 0).
// Double-buffered; natural block mapping (round-4 lesson: no blockIdx swizzle).
// Epilogue scatters bf16 into qkv: Q,K as [which][64][1024][96]; V third TRANSPOSED
// as [64][96][1024] with columns PERMUTED within 32-token blocks (tau) for attn's
// zero-shuffle PV.
__global__ __launch_bounds__(256)
void gemm_qkv(const float* __restrict__ x,
              const unsigned short* __restrict__ Bt,
              unsigned short* __restrict__ obf) {
  __shared__ unsigned short Asm[2][128 * 32];   // 2 x 8 KB, swizzled at ds_write
  __shared__ unsigned short Bsm[2][128 * 32];   // 2 x 8 KB, gl16 dest (source-swizzled)
  const int tid = threadIdx.x;
  const int wave = tid >> 6, lane = tid & 63;
  const int quad = lane >> 4, l16 = lane & 15;
  const int bm = blockIdx.x, bn = blockIdx.y;
  const int wm = (wave >> 1) * 64, wn = (wave & 1) * 64;

  f32x4 zero = {0.f, 0.f, 0.f, 0.f};
  f32x4 acc[4][4];
#pragma unroll
  for (int i = 0; i < 4; i++)
#pragma unroll
    for (int j = 0; j < 4; j++) acc[i][j] = zero;

  // A map: thread t covers row r = t>>1, 32B half h = t&1 (16 fp32 -> 16 bf16)
  const int ar = tid >> 1, ah = tid & 1;
  const float* xg = x + (size_t)(bm * 128 + ar) * Kz + ah * 16;
  const int s4 = (ar >> 1) & 3;                       // swizzle key of row ar
  const int ca = ((2 * ah) ^ s4) << 3;                // element offsets of the two chunks
  const int cb = ((2 * ah + 1) ^ s4) << 3;

  // B map: gl16, issue g covers rows g*64 + wave*16 + (lane>>2); source pre-swizzled
  const int sch = (lane & 3) ^ ((lane >> 3) & 3);     // lane-constant
  const unsigned short* Bgp = Bt + (size_t)(bn * 128 + wave * 16 + (lane >> 2)) * Kz + sch * 8;
  const int ldst = (wave * 16) * 32;

  float4 xv0, xv1, xv2, xv3;
#define LOADX(K) { xv0 = *(const float4*)(xg + (K));      xv1 = *(const float4*)(xg + (K) + 4); \
                   xv2 = *(const float4*)(xg + (K) + 8);  xv3 = *(const float4*)(xg + (K) + 12); }
#define STOREA(B) { uint4 da = { cvtpk(xv0.x, xv0.y), cvtpk(xv0.z, xv0.w),                      \
                                 cvtpk(xv1.x, xv1.y), cvtpk(xv1.z, xv1.w) };                    \
                    uint4 db = { cvtpk(xv2.x, xv2.y), cvtpk(xv2.z, xv2.w),                      \
                                 cvtpk(xv3.x, xv3.y), cvtpk(xv3.z, xv3.w) };                    \
                    *(uint4*)&Asm[B][ar * 32 + ca] = da;                                        \
                    *(uint4*)&Asm[B][ar * 32 + cb] = db; }

  // prologue: stage tile 0 into buf 0
  LOADX(0);
#pragma unroll
  for (int g = 0; g < 2; g++) gl16(Bgp + g * 64 * Kz, &Bsm[0][g * 2048 + ldst]);
  STOREA(0);
  __syncthreads();                     // drains vmcnt(0)+lgkmcnt: buf0 ready

  const int rc = (quad ^ ((l16 >> 1) & 3)) << 3;      // swizzled read chunk (elements)
  int cur = 0;
  for (int t = 0; t < Kz / 32; t++) {
    const int nxt = (t + 1) * 32;
    if (t + 1 < Kz / 32) {             // issue next tile's loads early (T14)
      LOADX(nxt);
#pragma unroll
      for (int g = 0; g < 2; g++) gl16(Bgp + g * 64 * Kz + nxt, &Bsm[cur ^ 1][g * 2048 + ldst]);
    }
    bf16x8 af[4], bfr[4];
#pragma unroll
    for (int mi = 0; mi < 4; mi++)
      af[mi] = *(const bf16x8*)&Asm[cur][(wm + mi * 16 + l16) * 32 + rc];
#pragma unroll
    for (int ni = 0; ni < 4; ni++)
      bfr[ni] = *(const bf16x8*)&Bsm[cur][(wn + ni * 16 + l16) * 32 + rc];
#pragma unroll
    for (int mi = 0; mi < 4; mi++)
#pragma unroll
      for (int ni = 0; ni < 4; ni++)
        acc[mi][ni] = __builtin_amdgcn_mfma_f32_16x16x32_bf16(af[mi], bfr[ni], acc[mi][ni], 0, 0, 0);
    if (t + 1 < Kz / 32) STOREA(cur ^ 1);   // cvt+write late: x latency hid under MFMA
    __syncthreads();                   // vmcnt(0)+lgkmcnt(0)+barrier: next buf ready, WAR safe
    cur ^= 1;
  }

#pragma unroll
  for (int mi = 0; mi < 4; mi++) {
    int row = bm * 128 + wm + mi * 16 + quad * 4;
    int b = row >> 10;
    int t = row & 1023;
#pragma unroll
    for (int ni = 0; ni < 4; ni++) {
      int col = bn * 128 + wn + ni * 16 + l16;
      int which = col / 768;          // wave-uniform per fragment (16 | 768)
      int cc = col - which * 768;
      int h = cc / 96;
      int d = cc - h * 96;
      if (which == 2) {
        // V^T layout [bh][d][t'], t' = k-order permutation of t within 32-blocks
        int tp = (t & ~31) | (((t >> 2) & 3) << 3) | (((t >> 4) & 1) << 2) | (t & 3);
        int base = ((2 * 64 + b * 8 + h) * 96 + d) * 1024 + tp;
        union { unsigned short s[4]; uint2 u; } o;
#pragma unroll
        for (int r = 0; r < 4; r++) o.s[r] = f2bf(acc[mi][ni][r]);
        *(uint2*)(obf + base) = o.u;
      } else {
        int base = ((which * 64 + b * 8 + h) * 1024 + t) * 96 + d;
#pragma unroll
        for (int r = 0; r < 4; r++) obf[base + r * 96] = f2bf(acc[mi][ni][r]);
      }
    }
  }
#undef LOADX
#undef STOREA
}

// ---- gemm_out: y[8192x768 bf16] @ Wpt^T -> out fp32; 64x128 tile (768 blocks = 3/CU) ----
__global__ __launch_bounds__(256)
void gemm_out(const unsigned short* __restrict__ A,
              const unsigned short* __restrict__ Bt,
              float* __restrict__ of32) {
  __shared__ unsigned short Asm[2][64 * 32];
  __shared__ unsigned short Bsm[2][128 * 32];
  const int tid = threadIdx.x;
  const int wave = tid >> 6, lane = tid & 63;
  const int quad = lane >> 4, l16 = lane & 15;
  const int bm = blockIdx.x, bn = blockIdx.y;
  const int wm = (wave >> 1) * 32, wn = (wave & 1) * 64;

  f32x4 zero = {0.f, 0.f, 0.f, 0.f};
  f32x4 acc[2][4];
#pragma unroll
  for (int i = 0; i < 2; i++)
#pragma unroll
    for (int j = 0; j < 4; j++) acc[i][j] = zero;

  const int sch = (lane & 3) ^ ((lane >> 3) & 3);     // lane-constant source swizzle
  const unsigned short* Agp = A + (size_t)(bm * 64 + wave * 16 + (lane >> 2)) * Kz + sch * 8;
  const unsigned short* Bgp = Bt + (size_t)(bn * 128 + wave * 16 + (lane >> 2)) * Kz + sch * 8;
  const int ldst = (wave * 16) * 32;

  gl16(Agp, &Asm[0][ldst]);
#pragma unroll
  for (int g = 0; g < 2; g++) gl16(Bgp + g * 64 * Kz, &Bsm[0][g * 2048 + ldst]);
  __syncthreads();

  const int rc = (quad ^ ((l16 >> 1) & 3)) << 3;
  int cur = 0;
  for (int t = 0; t < Kz / 32; t++) {
    if (t + 1 < Kz / 32) {
      const int kn = (t + 1) * 32;
      gl16(Agp + kn, &Asm[cur ^ 1][ldst]);
#pragma unroll
      for (int g = 0; g < 2; g++) gl16(Bgp + g * 64 * Kz + kn, &Bsm[cur ^ 1][g * 2048 + ldst]);
    }
    bf16x8 af[2], bfr[4];
#pragma unroll
    for (int mi = 0; mi < 2; mi++)
      af[mi] = *(const bf16x8*)&Asm[cur][(wm + mi * 16 + l16) * 32 + rc];
#pragma unroll
    for (int ni = 0; ni < 4; ni++)
      bfr[ni] = *(const bf16x8*)&Bsm[cur][(wn + ni * 16 + l16) * 32 + rc];
#pragma unroll
    for (int mi = 0; mi < 2; mi++)
#pragma unroll
      for (int ni = 0; ni < 4; ni++)
        acc[mi][ni] = __builtin_amdgcn_mfma_f32_16x16x32_bf16(af[mi], bfr[ni], acc[mi][ni], 0, 0, 0);
    __syncthreads();
    cur ^= 1;
  }

#pragma unroll
  for (int mi = 0; mi < 2; mi++) {
    int row = bm * 64 + wm + mi * 16 + quad * 4;
#pragma unroll
    for (int ni = 0; ni < 4; ni++) {
      int col = bn * 128 + wn + ni * 16 + l16;
#pragma unroll
      for (int r = 0; r < 4; r++) of32[(row + r) * 768 + col] = acc[mi][ni][r];
    }
  }
}

// ---- flash attention: 1 block = (b,h) x 64 q-rows; 4 waves x 16 rows; BS=128 ----
// (r10/r11 structure: safe-exp softmax, zero-shuffle PV, gl16 V staging,
//  class-balanced q-tile map — unchanged)
__global__ __launch_bounds__(256, 4)
void attn(const unsigned short* __restrict__ qkv, unsigned short* __restrict__ y) {
  const int bh = blockIdx.x;
  const int by = blockIdx.y;
  const int gcl = by & 3, kcl = by >> 2;
  const int j = (kcl == 0) ? (15 - gcl) : (kcl == 1) ? (8 + gcl)
              : (kcl == 2) ? (4 + gcl) : (3 - gcl);   // classes: {15,8,4,3}{14,9,5,2}{13,10,6,1}{12,11,7,0}
  const int q0 = j * 64;                   // heavy tiles (k=0) dispatch first
  const int tid = threadIdx.x;
  const int wave = tid >> 6, lane = tid & 63;
  const int quad = lane >> 4, l16 = lane & 15;
  const int qw0 = q0 + wave * 16;          // this wave's 16 q-rows (1 m-tile)
  const int b = bh >> 3, h = bh & 7;

  const unsigned short* Qh = qkv + bh * Tz * Dz;
  const unsigned short* Kh = qkv + (BHz + bh) * Tz * Dz;
  const unsigned short* Vt = qkv + 2 * BHz * Tz * Dz + bh * Dz * Tz;  // V^T [d][t'], permuted

  __shared__ unsigned short Vsm[96 * 128];       // linear (gl16 dest), source-swizzled

  bf16x8 aq[3];                            // Q as MFMA B-operand: lane holds Q[q=l16][d..]
#pragma unroll
  for (int kd = 0; kd < 3; kd++)
    aq[kd] = *(const bf16x8*)(Qh + (qw0 + l16) * Dz + kd * 32 + quad * 8);

  f32x4 zero = {0.f, 0.f, 0.f, 0.f};
  f32x4 acc_o[6];
#pragma unroll
  for (int i = 0; i < 6; i++) acc_o[i] = zero;
  const float NEG = -__builtin_inff();
  float lrow = 0.f;                        // per-lane partial row-sum of q-row (qw0+l16)
  const float cs = 0.14724538519872735f;   // (1/sqrt(96)) * log2(e): exp2-domain softmax
  const int t_abs = qw0 + l16;             // this lane's q-row

  // V staging map (per wave-issue g): rows wave*24 + g*4 .. +3, lane -> row +(lane>>4),
  // chunk lane&15; global source chunk pre-swizzled: c ^ (row&7)
  const int vrow = wave * 24 + (lane >> 4);      // row of THIS lane at g=0 (g adds 4)
  const int vch = lane & 15;

  const int s_last = (q0 >> 7) << 7;       // floor(q0/128)*128
  for (int s0 = 0; s0 <= s_last; s0 += 128) {
    __syncthreads();                 // WAR: prior iter's Vsm reads done
    // ---- async V^T tile -> LDS (drains at the pre-PV barrier; hides under QK^T) ----
#pragma unroll
    for (int g = 0; g < 6; g++) {
      const int row = vrow + g * 4;
      gl16(Vt + row * Tz + s0 + ((vch ^ (row & 7)) << 3),
           &Vsm[(wave * 24 + g * 4) * 128]);
    }

    const int srem = qw0 + 15 - s0;              // >= 15 always; srem%16==15
    const int nlim = min(7, srem >> 4);          // last 16-wide s tile with unmasked cols
    const int klim = min(3, srem >> 5);          // last 32-wide PV k chunk

    // ---- S^T = K Q^T (swapped operands; lane holds S[s=quad*4+r][q=l16]) ----
    f32x4 sacc[8];
#pragma unroll
    for (int ni = 0; ni < 8; ni++) {
      if (ni <= nlim) {
        sacc[ni] = zero;
#pragma unroll
        for (int kd = 0; kd < 3; kd++) {
          bf16x8 bk = *(const bf16x8*)(Kh + (s0 + ni * 16 + l16) * Dz + kd * 32 + quad * 8);
          sacc[ni] = __builtin_amdgcn_mfma_f32_16x16x32_bf16(bk, aq[kd], sacc[ni], 0, 0, 0);
        }
      }
    }

    // ---- causal mask (diagonal-straddling tiles only; wave-uniform test) ----
#pragma unroll
    for (int ni = 0; ni < 8; ni++) {
      if (ni <= nlim && s0 + ni * 16 + 15 > qw0) {
        const int s_base = s0 + ni * 16 + quad * 4;
#pragma unroll
        for (int r = 0; r < 4; r++)
          if (s_base + r > t_abs) sacc[ni][r] = NEG;
      }
    }

    // ---- safe-exp softmax: p = exp2(s*cs) directly (no max tracking) ----
    float rs[4] = {0.f, 0.f, 0.f, 0.f};
    unsigned int pk[8][2];                       // packed bf16x2: tile ni, s pairs
#pragma unroll
    for (int ni = 0; ni < 8; ni++) {
      if (ni <= nlim) {
        float p0 = EXP2(sacc[ni][0] * cs);       // masked: exp2(-inf)=0
        float p1 = EXP2(sacc[ni][1] * cs);
        float p2 = EXP2(sacc[ni][2] * cs);
        float p3 = EXP2(sacc[ni][3] * cs);
        rs[0] += p0; rs[1] += p1; rs[2] += p2; rs[3] += p3;
        pk[ni][0] = cvtpk(p0, p1);
        pk[ni][1] = cvtpk(p2, p3);
      } else {
        pk[ni][0] = 0u; pk[ni][1] = 0u;
      }
    }
    lrow += (rs[0] + rs[1]) + (rs[2] + rs[3]);   // per-lane partial; reduce at end

    __syncthreads();                 // drains vmcnt(0): Vsm ready

    // ---- O += P V : zero-shuffle — V columns pre-permuted to P's k-order ----
#pragma unroll
    for (int kc = 0; kc < 4; kc++) {
      if (kc <= klim) {
        union { unsigned int w[4]; bf16x8 v; } ap;
        ap.w[0] = pk[2 * kc][0];
        ap.w[1] = pk[2 * kc][1];
        ap.w[2] = pk[2 * kc + 1][0];
        ap.w[3] = pk[2 * kc + 1][1];
#pragma unroll
        for (int di = 0; di < 6; di++) {
          // read swizzle matches the pre-swizzled source: chunk ^= (row&7), row&7 == l16&7
          bf16x8 bv = *(const bf16x8*)&Vsm[(di * 16 + l16) * 128 +
                                           (((kc * 4 + quad) ^ (l16 & 7)) << 3)];
          acc_o[di] = __builtin_amdgcn_mfma_f32_16x16x32_bf16(ap.v, bv, acc_o[di], 0, 0, 0);
        }
      }
    }
  }

  // ---- epilogue: reduce l across quad-partners, normalize, store ----
  lrow += __shfl_xor(lrow, 16);
  lrow += __shfl_xor(lrow, 32);              // lane holds full sum of its q-row
  float linv = 1.f / lrow;
  float lv[4];
#pragma unroll
  for (int r = 0; r < 4; r++) lv[r] = __shfl(linv, quad * 4 + r);
#pragma unroll
  for (int r = 0; r < 4; r++) {
    int t = qw0 + quad * 4 + r;
#pragma unroll
    for (int di = 0; di < 6; di++) {
      int d = di * 16 + l16;
      y[(b * Tz + t) * Cz + h * Dz + d] = f2bf(acc_o[di][r] * lv[r]);
    }
  }
}

// ---- workspace layout (bytes) ----
#define OFF_WAT  0u                   // 2304*768*2 = 3538944
#define OFF_WPT  3538944u             // + 768*768*2 = 1179648
#define OFF_QKV  4718592u             // + 3*64*1024*96*2 = 37748736
#define OFF_Y    42467328u            // + 8192*768*2

extern "C" void kernel_launch(void* const* d_in, const int* in_sizes, int n_in,
                              void* d_out, int out_size, void* d_ws, size_t ws_size,
                              hipStream_t stream) {
  const float* x  = (const float*)d_in[0];
  const float* Wa = (const float*)d_in[1];
  const float* Wp = (const float*)d_in[2];
  float* out = (float*)d_out;
  uint8_t* ws = (uint8_t*)d_ws;
  unsigned short* Wat = (unsigned short*)(ws + OFF_WAT);
  unsigned short* Wpt = (unsigned short*)(ws + OFF_WPT);
  unsigned short* qkv = (unsigned short*)(ws + OFF_QKV);
  unsigned short* y   = (unsigned short*)(ws + OFF_Y);

  prep<<<576, 256, 0, stream>>>(Wa, Wat, Wp, Wpt);
  gemm_qkv<<<dim3(64, 18), 256, 0, stream>>>(x, Wat, qkv);
  attn<<<dim3(64, 16), 256, 0, stream>>>(qkv, y);
  gemm_out<<<dim3(128, 6), 256, 0, stream>>>(y, Wpt, out);
}

// Round 13
// 195.070 us; speedup vs baseline: 1.0747x; 1.0747x over previous
//
#include <hip/hip_runtime.h>
#include <stdint.h>

// ---- problem constants ----
#define Bz 8
#define Tz 1024
#define Cz 768
#define Hz 8
#define Dz 96
#define BHz 64            // Bz*Hz
#define Kz 768

typedef __bf16 bf16x8 __attribute__((ext_vector_type(8)));
typedef unsigned short u16x8 __attribute__((ext_vector_type(8)));
typedef float f32x4 __attribute__((ext_vector_type(4)));

__device__ __forceinline__ unsigned short f2bf(float f) {
  union { float f; unsigned int u; } v; v.f = f;
  unsigned int u = v.u;
  return (unsigned short)((u + 0x7fffu + ((u >> 16) & 1u)) >> 16);
}

// pack two f32 -> one dword of 2x bf16 (lo=a, hi=b); gfx950 hw instr (guide T12)
__device__ __forceinline__ unsigned int cvtpk(float a, float b) {
  unsigned int r;
  asm("v_cvt_pk_bf16_f32 %0, %1, %2" : "=v"(r) : "v"(a), "v"(b));
  return r;
}

#if defined(__has_builtin)
#if __has_builtin(__builtin_amdgcn_exp2f)
#define EXP2(x) __builtin_amdgcn_exp2f(x)
#endif
#endif
#ifndef EXP2
#define EXP2(x) __expf((x) * 0.6931471805599453f)
#endif

// async global->LDS, 16B per lane; LDS dest must be wave-uniform base (+lane*16 implicit)
typedef const __attribute__((address_space(1))) void* gas_ptr;
typedef __attribute__((address_space(3))) void* las_ptr;
__device__ __forceinline__ void gl16(const void* g, void* l) {
  __builtin_amdgcn_global_load_lds((gas_ptr)g, (las_ptr)l, 16, 0, 0);
}

// ---- fused prep: cast x->bf16 (blocks 0..6143), transpose Wa (..6575), Wp (..6719) ----
__global__ __launch_bounds__(256) void prep(const float* __restrict__ x,
                                            unsigned short* __restrict__ xb,
                                            const float* __restrict__ Wa,
                                            unsigned short* __restrict__ Wat,
                                            const float* __restrict__ Wp,
                                            unsigned short* __restrict__ Wpt) {
  __shared__ unsigned short t[64][72];
  const int bid = blockIdx.x;
  const int tid = threadIdx.x;
  if (bid < 6144) {
    int i = (bid * 256 + tid) * 4;
    float4 v = *(const float4*)(x + i);
    union { unsigned short s[4]; uint2 u; } o;
    o.s[0] = f2bf(v.x); o.s[1] = f2bf(v.y); o.s[2] = f2bf(v.z); o.s[3] = f2bf(v.w);
    *(uint2*)(xb + i) = o.u;
    return;
  }
  const float* in; unsigned short* out; int R, Cc, bx, by;
  if (bid < 6576) { int q = bid - 6144; in = Wa; out = Wat; R = 768; Cc = 2304; bx = (q % 36) * 64; by = (q / 36) * 64; }
  else            { int q = bid - 6576; in = Wp; out = Wpt; R = 768; Cc = 768;  bx = (q % 12) * 64; by = (q / 12) * 64; }
#pragma unroll
  for (int i = 0; i < 16; i++) {
    int idx = tid + i * 256;
    int r = idx >> 6, c = idx & 63;
    t[c][r] = f2bf(in[(by + r) * Cc + bx + c]);
  }
  __syncthreads();
#pragma unroll
  for (int i = 0; i < 16; i++) {
    int idx = tid + i * 256;
    int r = idx >> 6, c = idx & 63;
    out[(bx + r) * R + by + c] = t[r][c];
  }
}

// ---- BMx128 MFMA bf16 GEMM, BK=32, double-buffered with COUNTED VMCNT (T4) ----
// r12 lesson: __syncthreads drains vmcnt(0), killing the dbuf prefetch (r9 null
// explained). Here: per iter {issue next-tile gl16 -> s_waitcnt vmcnt(NISS) ->
// s_barrier -> ds_read+MFMA -> s_barrier}. The counted wait leaves the next tile's
// NISS loads in flight across the barrier and the whole MFMA phase (m218 pattern).
// WAR: issue at t targets the buffer whose reads finished at t-1's post-compute
// barrier. Swizzle (validated, conflicts=0): source chunk ^((lane>>3)&3), read
// chunk quad^((l16>>1)&3). Natural block mapping (round-4 lesson: no XCD swizzle).
// MODE 0: epilogue scatters bf16 into qkv: Q,K as [which][64][1024][96];
//         V third TRANSPOSED as [64][96][1024] with tau-permuted columns.
// MODE 1: epilogue writes fp32 C[M][768]
template <int MODE, int BM>
__global__ __launch_bounds__(256)
void gemm128(const unsigned short* __restrict__ A,
             const unsigned short* __restrict__ Bt,
             unsigned short* __restrict__ obf,
             float* __restrict__ of32) {
  constexpr int MW = BM / 2;           // rows per wave-row group (64 or 32)
  constexpr int MFR = MW / 16;         // acc fragment rows (4 or 2)
  constexpr int GA = BM / 64;          // A staging issues (2 or 1)
  constexpr int NT = Kz / 32;          // 24 K-tiles
  __shared__ unsigned short Asm[2][BM * 32];
  __shared__ unsigned short Bsm[2][128 * 32];
  const int tid = threadIdx.x;
  const int wave = tid >> 6, lane = tid & 63;
  const int quad = lane >> 4, l16 = lane & 15;
  const int bm = blockIdx.x, bn = blockIdx.y;
  const int wm = (wave >> 1) * MW, wn = (wave & 1) * 64;

  f32x4 zero = {0.f, 0.f, 0.f, 0.f};
  f32x4 acc[MFR][4];
#pragma unroll
  for (int i = 0; i < MFR; i++)
#pragma unroll
    for (int j = 0; j < 4; j++) acc[i][j] = zero;

  // staging: issue g covers rows g*64 + wave*16 + (lane>>2); source chunk pre-swizzled
  const int sch = (lane & 3) ^ ((lane >> 3) & 3);     // lane-constant
  const unsigned short* Agp = A + (size_t)(bm * BM + wave * 16 + (lane >> 2)) * Kz + sch * 8;
  const unsigned short* Bgp = Bt + (size_t)(bn * 128 + wave * 16 + (lane >> 2)) * Kz + sch * 8;
  const int ldst = (wave * 16) * 32;                  // element offset of this wave's dest

  // prologue: stage tile 0 into buf 0 (NISS = GA+2 gl16 per thread in flight)
#pragma unroll
  for (int g = 0; g < GA; g++) gl16(Agp + g * 64 * Kz, &Asm[0][g * 2048 + ldst]);
#pragma unroll
  for (int g = 0; g < 2; g++)  gl16(Bgp + g * 64 * Kz, &Bsm[0][g * 2048 + ldst]);

  const int rc = (quad ^ ((l16 >> 1) & 3)) << 3;      // swizzled read chunk (elements)
  int cur = 0;
  for (int t = 0; t < NT; t++) {
    if (t + 1 < NT) {                  // issue next tile; loads stay in flight (T4)
      const int kn = (t + 1) * 32;
#pragma unroll
      for (int g = 0; g < GA; g++) gl16(Agp + g * 64 * Kz + kn, &Asm[cur ^ 1][g * 2048 + ldst]);
#pragma unroll
      for (int g = 0; g < 2; g++)  gl16(Bgp + g * 64 * Kz + kn, &Bsm[cur ^ 1][g * 2048 + ldst]);
      if (BM == 128) asm volatile("s_waitcnt vmcnt(4)" ::: "memory");
      else           asm volatile("s_waitcnt vmcnt(3)" ::: "memory");
    } else {
      asm volatile("s_waitcnt vmcnt(0)" ::: "memory");
    }
    __builtin_amdgcn_sched_barrier(0);
    __builtin_amdgcn_s_barrier();      // tile t staged by all waves (each drained its own)
    __builtin_amdgcn_sched_barrier(0);
    bf16x8 af[MFR], bfr[4];
#pragma unroll
    for (int mi = 0; mi < MFR; mi++)
      af[mi] = *(const bf16x8*)&Asm[cur][(wm + mi * 16 + l16) * 32 + rc];
#pragma unroll
    for (int ni = 0; ni < 4; ni++)
      bfr[ni] = *(const bf16x8*)&Bsm[cur][(wn + ni * 16 + l16) * 32 + rc];
#pragma unroll
    for (int mi = 0; mi < MFR; mi++)
#pragma unroll
      for (int ni = 0; ni < 4; ni++)
        acc[mi][ni] = __builtin_amdgcn_mfma_f32_16x16x32_bf16(af[mi], bfr[ni], acc[mi][ni], 0, 0, 0);
    __builtin_amdgcn_sched_barrier(0);
    __builtin_amdgcn_s_barrier();      // all waves done reading buf[cur] (WAR for next issue)
    cur ^= 1;
  }

#pragma unroll
  for (int mi = 0; mi < MFR; mi++) {
    int row = bm * BM + wm + mi * 16 + quad * 4;
    if (MODE == 0) {
      int b = row >> 10;
      int t = row & 1023;
#pragma unroll
      for (int ni = 0; ni < 4; ni++) {
        int col = bn * 128 + wn + ni * 16 + l16;
        int which = col / 768;        // wave-uniform per fragment (16 | 768)
        int cc = col - which * 768;
        int h = cc / 96;
        int d = cc - h * 96;
        if (which == 2) {
          // V^T layout [bh][d][t'], t' = k-order permutation of t within 32-blocks
          int tp = (t & ~31) | (((t >> 2) & 3) << 3) | (((t >> 4) & 1) << 2) | (t & 3);
          int base = ((2 * 64 + b * 8 + h) * 96 + d) * 1024 + tp;
          union { unsigned short s[4]; uint2 u; } o;
#pragma unroll
          for (int r = 0; r < 4; r++) o.s[r] = f2bf(acc[mi][ni][r]);
          *(uint2*)(obf + base) = o.u;
        } else {
          int base = ((which * 64 + b * 8 + h) * 1024 + t) * 96 + d;
#pragma unroll
          for (int r = 0; r < 4; r++) obf[base + r * 96] = f2bf(acc[mi][ni][r]);
        }
      }
    } else {
#pragma unroll
      for (int ni = 0; ni < 4; ni++) {
        int col = bn * 128 + wn + ni * 16 + l16;
#pragma unroll
        for (int r = 0; r < 4; r++) of32[(row + r) * 768 + col] = acc[mi][ni][r];
      }
    }
  }
}

// ---- flash attention: 1 block = (b,h) x 64 q-rows; 4 waves x 16 rows; BS=128 ----
// (r10/r11 structure: safe-exp softmax, zero-shuffle PV, gl16 V staging,
//  class-balanced q-tile map — unchanged)
__global__ __launch_bounds__(256, 4)
void attn(const unsigned short* __restrict__ qkv, unsigned short* __restrict__ y) {
  const int bh = blockIdx.x;
  const int by = blockIdx.y;
  const int gcl = by & 3, kcl = by >> 2;
  const int j = (kcl == 0) ? (15 - gcl) : (kcl == 1) ? (8 + gcl)
              : (kcl == 2) ? (4 + gcl) : (3 - gcl);   // classes: {15,8,4,3}{14,9,5,2}{13,10,6,1}{12,11,7,0}
  const int q0 = j * 64;                   // heavy tiles (k=0) dispatch first
  const int tid = threadIdx.x;
  const int wave = tid >> 6, lane = tid & 63;
  const int quad = lane >> 4, l16 = lane & 15;
  const int qw0 = q0 + wave * 16;          // this wave's 16 q-rows (1 m-tile)
  const int b = bh >> 3, h = bh & 7;

  const unsigned short* Qh = qkv + bh * Tz * Dz;
  const unsigned short* Kh = qkv + (BHz + bh) * Tz * Dz;
  const unsigned short* Vt = qkv + 2 * BHz * Tz * Dz + bh * Dz * Tz;  // V^T [d][t'], permuted

  __shared__ unsigned short Vsm[96 * 128];       // linear (gl16 dest), source-swizzled

  bf16x8 aq[3];                            // Q as MFMA B-operand: lane holds Q[q=l16][d..]
#pragma unroll
  for (int kd = 0; kd < 3; kd++)
    aq[kd] = *(const bf16x8*)(Qh + (qw0 + l16) * Dz + kd * 32 + quad * 8);

  f32x4 zero = {0.f, 0.f, 0.f, 0.f};
  f32x4 acc_o[6];
#pragma unroll
  for (int i = 0; i < 6; i++) acc_o[i] = zero;
  const float NEG = -__builtin_inff();
  float lrow = 0.f;                        // per-lane partial row-sum of q-row (qw0+l16)
  const float cs = 0.14724538519872735f;   // (1/sqrt(96)) * log2(e): exp2-domain softmax
  const int t_abs = qw0 + l16;             // this lane's q-row

  // V staging map (per wave-issue g): rows wave*24 + g*4 .. +3, lane -> row +(lane>>4),
  // chunk lane&15; global source chunk pre-swizzled: c ^ (row&7)
  const int vrow = wave * 24 + (lane >> 4);      // row of THIS lane at g=0 (g adds 4)
  const int vch = lane & 15;

  const int s_last = (q0 >> 7) << 7;       // floor(q0/128)*128
  for (int s0 = 0; s0 <= s_last; s0 += 128) {
    __syncthreads();                 // WAR: prior iter's Vsm reads done
    // ---- async V^T tile -> LDS (drains at the pre-PV barrier; hides under QK^T) ----
#pragma unroll
    for (int g = 0; g < 6; g++) {
      const int row = vrow + g * 4;
      gl16(Vt + row * Tz + s0 + ((vch ^ (row & 7)) << 3),
           &Vsm[(wave * 24 + g * 4) * 128]);
    }

    const int srem = qw0 + 15 - s0;              // >= 15 always; srem%16==15
    const int nlim = min(7, srem >> 4);          // last 16-wide s tile with unmasked cols
    const int klim = min(3, srem >> 5);          // last 32-wide PV k chunk

    // ---- S^T = K Q^T (swapped operands; lane holds S[s=quad*4+r][q=l16]) ----
    f32x4 sacc[8];
#pragma unroll
    for (int ni = 0; ni < 8; ni++) {
      if (ni <= nlim) {
        sacc[ni] = zero;
#pragma unroll
        for (int kd = 0; kd < 3; kd++) {
          bf16x8 bk = *(const bf16x8*)(Kh + (s0 + ni * 16 + l16) * Dz + kd * 32 + quad * 8);
          sacc[ni] = __builtin_amdgcn_mfma_f32_16x16x32_bf16(bk, aq[kd], sacc[ni], 0, 0, 0);
        }
      }
    }

    // ---- causal mask (diagonal-straddling tiles only; wave-uniform test) ----
#pragma unroll
    for (int ni = 0; ni < 8; ni++) {
      if (ni <= nlim && s0 + ni * 16 + 15 > qw0) {
        const int s_base = s0 + ni * 16 + quad * 4;
#pragma unroll
        for (int r = 0; r < 4; r++)
          if (s_base + r > t_abs) sacc[ni][r] = NEG;
      }
    }

    // ---- safe-exp softmax: p = exp2(s*cs) directly (no max tracking) ----
    float rs[4] = {0.f, 0.f, 0.f, 0.f};
    unsigned int pk[8][2];                       // packed bf16x2: tile ni, s pairs
#pragma unroll
    for (int ni = 0; ni < 8; ni++) {
      if (ni <= nlim) {
        float p0 = EXP2(sacc[ni][0] * cs);       // masked: exp2(-inf)=0
        float p1 = EXP2(sacc[ni][1] * cs);
        float p2 = EXP2(sacc[ni][2] * cs);
        float p3 = EXP2(sacc[ni][3] * cs);
        rs[0] += p0; rs[1] += p1; rs[2] += p2; rs[3] += p3;
        pk[ni][0] = cvtpk(p0, p1);
        pk[ni][1] = cvtpk(p2, p3);
      } else {
        pk[ni][0] = 0u; pk[ni][1] = 0u;
      }
    }
    lrow += (rs[0] + rs[1]) + (rs[2] + rs[3]);   // per-lane partial; reduce at end

    __syncthreads();                 // drains vmcnt(0): Vsm ready

    // ---- O += P V : zero-shuffle — V columns pre-permuted to P's k-order ----
#pragma unroll
    for (int kc = 0; kc < 4; kc++) {
      if (kc <= klim) {
        union { unsigned int w[4]; bf16x8 v; } ap;
        ap.w[0] = pk[2 * kc][0];
        ap.w[1] = pk[2 * kc][1];
        ap.w[2] = pk[2 * kc + 1][0];
        ap.w[3] = pk[2 * kc + 1][1];
#pragma unroll
        for (int di = 0; di < 6; di++) {
          // read swizzle matches the pre-swizzled source: chunk ^= (row&7), row&7 == l16&7
          bf16x8 bv = *(const bf16x8*)&Vsm[(di * 16 + l16) * 128 +
                                           (((kc * 4 + quad) ^ (l16 & 7)) << 3)];
          acc_o[di] = __builtin_amdgcn_mfma_f32_16x16x32_bf16(ap.v, bv, acc_o[di], 0, 0, 0);
        }
      }
    }
  }

  // ---- epilogue: reduce l across quad-partners, normalize, store ----
  lrow += __shfl_xor(lrow, 16);
  lrow += __shfl_xor(lrow, 32);              // lane holds full sum of its q-row
  float linv = 1.f / lrow;
  float lv[4];
#pragma unroll
  for (int r = 0; r < 4; r++) lv[r] = __shfl(linv, quad * 4 + r);
#pragma unroll
  for (int r = 0; r < 4; r++) {
    int t = qw0 + quad * 4 + r;
#pragma unroll
    for (int di = 0; di < 6; di++) {
      int d = di * 16 + l16;
      y[(b * Tz + t) * Cz + h * Dz + d] = f2bf(acc_o[di][r] * lv[r]);
    }
  }
}

// ---- workspace layout (bytes) ----
#define OFF_XB   0u
#define OFF_WAT  12582912u            // 8192*768*2
#define OFF_WPT  16121856u            // + 2304*768*2
#define OFF_QKV  17301504u            // + 768*768*2
#define OFF_Y    55050240u            // + 3*64*1024*96*2

extern "C" void kernel_launch(void* const* d_in, const int* in_sizes, int n_in,
                              void* d_out, int out_size, void* d_ws, size_t ws_size,
                              hipStream_t stream) {
  const float* x  = (const float*)d_in[0];
  const float* Wa = (const float*)d_in[1];
  const float* Wp = (const float*)d_in[2];
  float* out = (float*)d_out;
  uint8_t* ws = (uint8_t*)d_ws;
  unsigned short* xb  = (unsigned short*)(ws + OFF_XB);
  unsigned short* Wat = (unsigned short*)(ws + OFF_WAT);
  unsigned short* Wpt = (unsigned short*)(ws + OFF_WPT);
  unsigned short* qkv = (unsigned short*)(ws + OFF_QKV);
  unsigned short* y   = (unsigned short*)(ws + OFF_Y);

  prep<<<6720, 256, 0, stream>>>(x, xb, Wa, Wat, Wp, Wpt);
  gemm128<0, 128><<<dim3(64, 18), 256, 0, stream>>>(xb, Wat, qkv, nullptr);
  attn<<<dim3(64, 16), 256, 0, stream>>>(qkv, y);
  gemm128<1, 64><<<dim3(128, 6), 256, 0, stream>>>(y, Wpt, nullptr, out);
}